// Round 3
// baseline (257.548 us; speedup 1.0000x reference)
//
#include <hip/hip_runtime.h>

#define N_NODES 100000
#define N_EDGES 1600000
#define IN_CH 8
#define HID_CH 64
#define OUT_CH 2
#define K_SPLIT 4   // sub-chains per node: 4x memory-level parallelism in the chase

// Workspace layout (4-byte elements), total 2.2M * 4B = 8.8 MB:
//   head : K_SPLIT*N_NODES ints @ [0,       400000)   -> memset 0xFF = -1
//   next : N_EDGES ints         @ [400000, 2000000)   -> fully written by build_list
//   g    : N_NODES*2 float      @ [2000000,2200000)   (W_l2 @ h per node)
// rt (root term W_r2*h + b_l2) is stored directly in d_out by gather1.
#define WS_HEAD 0
#define WS_NEXT 400000
#define WS_G    2000000

__global__ void build_list(const int* __restrict__ dst,
                           int* __restrict__ head, int* __restrict__ next) {
    int e = blockIdx.x * blockDim.x + threadIdx.x;
    if (e >= N_EDGES) return;
    int d = dst[e];
    int old = atomicExch(&head[(e & (K_SPLIT - 1)) * N_NODES + d], e);
    next[e] = old;
}

// Phase 1: 4 threads per node chase 4 sub-chains, summing x[src] (8ch) in regs.
// Cross-lane reduce (width 4) -> LDS. Phase 2: 64 threads/block run the fused MLP:
//   h = relu(W_l1*aggr + b_l1 + W_r1*x_i);  g = W_l2*h;  out(rt) = W_r2*h + b_l2.
__global__ __launch_bounds__(256) void gather1_node(
        const int* __restrict__ src,
        const int* __restrict__ head, const int* __restrict__ next,
        const float* __restrict__ x,
        const float* __restrict__ W_l1, const float* __restrict__ b_l1,
        const float* __restrict__ W_r1,
        const float* __restrict__ W_l2, const float* __restrict__ b_l2,
        const float* __restrict__ W_r2,
        float* __restrict__ g, float* __restrict__ out_rt) {
    __shared__ float sWl[HID_CH * IN_CH];
    __shared__ float sWr[HID_CH * IN_CH];
    __shared__ float sb[HID_CH];
    __shared__ float sWl2[OUT_CH * HID_CH];
    __shared__ float sWr2[OUT_CH * HID_CH];
    __shared__ float sb2[OUT_CH];
    __shared__ float sAcc[64][IN_CH + 1];   // reduced sums + cnt per node

    for (int i = threadIdx.x; i < HID_CH * IN_CH; i += blockDim.x) {
        sWl[i] = W_l1[i];
        sWr[i] = W_r1[i];
    }
    for (int i = threadIdx.x; i < HID_CH; i += blockDim.x) sb[i] = b_l1[i];
    for (int i = threadIdx.x; i < OUT_CH * HID_CH; i += blockDim.x) {
        sWl2[i] = W_l2[i];
        sWr2[i] = W_r2[i];
    }
    if (threadIdx.x < OUT_CH) sb2[threadIdx.x] = b_l2[threadIdx.x];

    int t = blockIdx.x * blockDim.x + threadIdx.x;
    int node = t >> 2;
    int k = t & 3;

    float acc[IN_CH];
    #pragma unroll
    for (int c = 0; c < IN_CH; c++) acc[c] = 0.0f;
    int cnt = 0;

    if (node < N_NODES) {
        int e = head[k * N_NODES + node];
        while (e >= 0) {
            int en = next[e];             // dependent chain load first
            int s = src[e];
            const float4* xs = (const float4*)(x + (size_t)s * IN_CH);
            float4 a = xs[0];
            float4 b = xs[1];
            acc[0] += a.x; acc[1] += a.y; acc[2] += a.z; acc[3] += a.w;
            acc[4] += b.x; acc[5] += b.y; acc[6] += b.z; acc[7] += b.w;
            cnt++;
            e = en;
        }
    }

    // Reduce the 4 sub-chain partials within each group of 4 lanes.
    #pragma unroll
    for (int c = 0; c < IN_CH; c++) {
        acc[c] += __shfl_xor(acc[c], 1, 4);
        acc[c] += __shfl_xor(acc[c], 2, 4);
    }
    cnt += __shfl_xor(cnt, 1, 4);
    cnt += __shfl_xor(cnt, 2, 4);

    int local = threadIdx.x >> 2;        // 0..63: node slot within block
    if (k == 0 && node < N_NODES) {
        #pragma unroll
        for (int c = 0; c < IN_CH; c++) sAcc[local][c] = acc[c];
        sAcc[local][IN_CH] = (float)cnt;
    }
    __syncthreads();

    if (threadIdx.x < 64) {
        int i = blockIdx.x * 64 + threadIdx.x;
        if (i < N_NODES) {
            float inv = 1.0f / fmaxf(sAcc[threadIdx.x][IN_CH], 1.0f);
            float ag[IN_CH], xa[IN_CH];
            #pragma unroll
            for (int c = 0; c < IN_CH; c++) ag[c] = sAcc[threadIdx.x][c] * inv;
            const float4* xp = (const float4*)(x + (size_t)i * IN_CH);
            float4 x0 = xp[0], x1 = xp[1];
            xa[0] = x0.x; xa[1] = x0.y; xa[2] = x0.z; xa[3] = x0.w;
            xa[4] = x1.x; xa[5] = x1.y; xa[6] = x1.z; xa[7] = x1.w;

            float g0 = 0.f, g1 = 0.f, r0 = 0.f, r1 = 0.f;
            #pragma unroll 8
            for (int kk = 0; kk < HID_CH; kk++) {
                float hk = sb[kk];
                #pragma unroll
                for (int c = 0; c < IN_CH; c++) {
                    hk += sWl[kk * IN_CH + c] * ag[c];
                    hk += sWr[kk * IN_CH + c] * xa[c];
                }
                hk = fmaxf(hk, 0.0f);    // ReLU (dropout identity in eval)
                g0 += sWl2[kk] * hk;
                g1 += sWl2[HID_CH + kk] * hk;
                r0 += sWr2[kk] * hk;
                r1 += sWr2[HID_CH + kk] * hk;
            }
            g[(size_t)i * 2 + 0] = g0;
            g[(size_t)i * 2 + 1] = g1;
            // Root term of layer 2 parked in d_out; gather2 adds the aggregate.
            float2 r;
            r.x = r0 + sb2[0];
            r.y = r1 + sb2[1];
            *(float2*)(out_rt + (size_t)i * 2) = r;
        }
    }
}

// 4 threads per node chase the same 4 sub-chains summing g[src] (2ch);
// shfl-reduce; lane 0 finalizes: out = sum/max(cnt,1) + rt (already in out).
__global__ __launch_bounds__(256) void gather2_node(
        const int* __restrict__ src,
        const int* __restrict__ head, const int* __restrict__ next,
        const float* __restrict__ g, float* __restrict__ out) {
    int t = blockIdx.x * blockDim.x + threadIdx.x;
    int node = t >> 2;
    int k = t & 3;

    float a0 = 0.f, a1 = 0.f;
    int cnt = 0;
    if (node < N_NODES) {
        int e = head[k * N_NODES + node];
        while (e >= 0) {
            int en = next[e];
            int s = src[e];
            float2 gv = *(const float2*)(g + (size_t)s * 2);
            a0 += gv.x;
            a1 += gv.y;
            cnt++;
            e = en;
        }
    }
    a0 += __shfl_xor(a0, 1, 4);
    a0 += __shfl_xor(a0, 2, 4);
    a1 += __shfl_xor(a1, 1, 4);
    a1 += __shfl_xor(a1, 2, 4);
    cnt += __shfl_xor(cnt, 1, 4);
    cnt += __shfl_xor(cnt, 2, 4);

    if (k == 0 && node < N_NODES) {
        float inv = 1.0f / fmaxf((float)cnt, 1.0f);
        float2 r = *(const float2*)(out + (size_t)node * 2);
        float2 o;
        o.x = a0 * inv + r.x;
        o.y = a1 * inv + r.y;
        *(float2*)(out + (size_t)node * 2) = o;
    }
}

extern "C" void kernel_launch(void* const* d_in, const int* in_sizes, int n_in,
                              void* d_out, int out_size, void* d_ws, size_t ws_size,
                              hipStream_t stream) {
    const float* x    = (const float*)d_in[0];
    const int*   ei   = (const int*)d_in[1];   // [2, N_EDGES] int32 per harness
    const float* W_l1 = (const float*)d_in[2];
    const float* b_l1 = (const float*)d_in[3];
    const float* W_r1 = (const float*)d_in[4];
    const float* W_l2 = (const float*)d_in[5];
    const float* b_l2 = (const float*)d_in[6];
    const float* W_r2 = (const float*)d_in[7];
    float* out = (float*)d_out;

    const int* src = ei;
    const int* dst = ei + N_EDGES;

    int*   head = (int*)d_ws + WS_HEAD;
    int*   next = (int*)d_ws + WS_NEXT;
    float* g    = (float*)d_ws + WS_G;

    // head = -1 everywhere. next/g fully overwritten each call.
    hipMemsetAsync(head, 0xFF, (size_t)K_SPLIT * N_NODES * sizeof(int), stream);

    const int BT = 256;
    int eblocks = (N_EDGES + BT - 1) / BT;
    int nblocks4 = (K_SPLIT * N_NODES + BT - 1) / BT;

    build_list<<<eblocks, BT, 0, stream>>>(dst, head, next);
    gather1_node<<<nblocks4, BT, 0, stream>>>(src, head, next, x,
                                              W_l1, b_l1, W_r1, W_l2, b_l2, W_r2,
                                              g, out);
    gather2_node<<<nblocks4, BT, 0, stream>>>(src, head, next, g, out);
}

// Round 4
// 212.451 us; speedup vs baseline: 1.2123x; 1.2123x over previous
//
#include <hip/hip_runtime.h>

#define N_NODES 100000
#define N_EDGES 1600000
#define IN_CH 8
#define HID_CH 64
#define OUT_CH 2

// ---- workspace layout (4-byte elements) ----
//   deg  : N_NODES        @ WS_DEG   (memset 0; atomicAdd counters == per-node degree)
//   off  : N_NODES        @ WS_OFF   (exclusive scan of deg)
//   bsum : 128            @ WS_BSUM  (scan block sums)
//   rank : N_EDGES        @ WS_RANK  (per-edge slot within its dst segment)
//   csr  : N_EDGES        @ WS_CSR   (src indices grouped by dst)
//   g    : N_NODES*2 f32  @ WS_G     (W_l2 @ h per node)
// rt (root term) is written directly into d_out by gather1; gather2 adds aggregate.
#define WS_DEG  0
#define WS_OFF  100000
#define WS_BSUM 200000
#define WS_RANK 200200
#define WS_CSR  1800200
#define WS_G    3400200

#define SCAN_BLOCKS 98   // ceil(100000 / 1024)

__global__ void count_rank(const int* __restrict__ dst,
                           int* __restrict__ deg, int* __restrict__ rank) {
    int e = blockIdx.x * blockDim.x + threadIdx.x;
    if (e >= N_EDGES) return;
    rank[e] = atomicAdd(&deg[dst[e]], 1);
}

// Exclusive scan of deg[N_NODES] -> off, 1024 elements per block.
__global__ void scan1(const int* __restrict__ deg, int* __restrict__ off,
                      int* __restrict__ bsum) {
    __shared__ int s[256];
    int t = threadIdx.x;
    int base = blockIdx.x * 1024 + t * 4;
    int4 v = make_int4(0, 0, 0, 0);
    if (base + 3 < N_NODES) {
        v = *(const int4*)(deg + base);
    } else {
        if (base + 0 < N_NODES) v.x = deg[base + 0];
        if (base + 1 < N_NODES) v.y = deg[base + 1];
        if (base + 2 < N_NODES) v.z = deg[base + 2];
        if (base + 3 < N_NODES) v.w = deg[base + 3];
    }
    int s0 = v.x, s1 = s0 + v.y, s2 = s1 + v.z, s3 = s2 + v.w;
    s[t] = s3;
    __syncthreads();
    for (int d = 1; d < 256; d <<= 1) {
        int val = (t >= d) ? s[t - d] : 0;
        __syncthreads();
        if (t >= d) s[t] += val;
        __syncthreads();
    }
    int excl = s[t] - s3;
    if (t == 255) bsum[blockIdx.x] = s[t];
    if (base + 0 < N_NODES) off[base + 0] = excl;
    if (base + 1 < N_NODES) off[base + 1] = excl + s0;
    if (base + 2 < N_NODES) off[base + 2] = excl + s1;
    if (base + 3 < N_NODES) off[base + 3] = excl + s2;
}

__global__ void scan2(int* __restrict__ bsum) {
    __shared__ int s[128];
    int t = threadIdx.x;
    int v = (t < SCAN_BLOCKS) ? bsum[t] : 0;
    s[t] = v;
    __syncthreads();
    for (int d = 1; d < 128; d <<= 1) {
        int val = (t >= d) ? s[t - d] : 0;
        __syncthreads();
        if (t >= d) s[t] += val;
        __syncthreads();
    }
    if (t < SCAN_BLOCKS) bsum[t] = s[t] - v;   // exclusive
}

__global__ void scan3(int* __restrict__ off, const int* __restrict__ bsum) {
    int i = blockIdx.x * blockDim.x + threadIdx.x;
    if (i < N_NODES) off[i] += bsum[i >> 10];
}

__global__ void scatter_csr(const int* __restrict__ src, const int* __restrict__ dst,
                            const int* __restrict__ rank, const int* __restrict__ off,
                            int* __restrict__ csr) {
    int e = blockIdx.x * blockDim.x + threadIdx.x;
    if (e >= N_EDGES) return;
    csr[off[dst[e]] + rank[e]] = src[e];
}

// 4 lanes per node walk the contiguous CSR segment (interleaved -> coalesced),
// summing x[src] (8ch) in regs; shfl-reduce -> LDS; 64 threads/block then run:
//   h = relu(W_l1*aggr + b_l1 + W_r1*x_i); g = W_l2*h; out(rt) = W_r2*h + b_l2.
__global__ __launch_bounds__(256) void gather1_csr(
        const int* __restrict__ csr, const int* __restrict__ off,
        const int* __restrict__ deg,
        const float* __restrict__ x,
        const float* __restrict__ W_l1, const float* __restrict__ b_l1,
        const float* __restrict__ W_r1,
        const float* __restrict__ W_l2, const float* __restrict__ b_l2,
        const float* __restrict__ W_r2,
        float* __restrict__ g, float* __restrict__ out_rt) {
    __shared__ float sWl[HID_CH * IN_CH];
    __shared__ float sWr[HID_CH * IN_CH];
    __shared__ float sb[HID_CH];
    __shared__ float sWl2[OUT_CH * HID_CH];
    __shared__ float sWr2[OUT_CH * HID_CH];
    __shared__ float sb2[OUT_CH];
    __shared__ float sAcc[64][IN_CH + 1];

    for (int i = threadIdx.x; i < HID_CH * IN_CH; i += blockDim.x) {
        sWl[i] = W_l1[i];
        sWr[i] = W_r1[i];
    }
    for (int i = threadIdx.x; i < HID_CH; i += blockDim.x) sb[i] = b_l1[i];
    for (int i = threadIdx.x; i < OUT_CH * HID_CH; i += blockDim.x) {
        sWl2[i] = W_l2[i];
        sWr2[i] = W_r2[i];
    }
    if (threadIdx.x < OUT_CH) sb2[threadIdx.x] = b_l2[threadIdx.x];

    int t = blockIdx.x * blockDim.x + threadIdx.x;
    int node = t >> 2;
    int k = t & 3;

    float acc[IN_CH];
    #pragma unroll
    for (int c = 0; c < IN_CH; c++) acc[c] = 0.0f;

    if (node < N_NODES) {
        int start = off[node];
        int dn = deg[node];
        for (int j = k; j < dn; j += 4) {
            int s = csr[start + j];
            const float4* xs = (const float4*)(x + (size_t)s * IN_CH);
            float4 a = xs[0];
            float4 b = xs[1];
            acc[0] += a.x; acc[1] += a.y; acc[2] += a.z; acc[3] += a.w;
            acc[4] += b.x; acc[5] += b.y; acc[6] += b.z; acc[7] += b.w;
        }
    }
    #pragma unroll
    for (int c = 0; c < IN_CH; c++) {
        acc[c] += __shfl_xor(acc[c], 1, 4);
        acc[c] += __shfl_xor(acc[c], 2, 4);
    }
    int local = threadIdx.x >> 2;
    if (k == 0 && node < N_NODES) {
        #pragma unroll
        for (int c = 0; c < IN_CH; c++) sAcc[local][c] = acc[c];
        sAcc[local][IN_CH] = (float)deg[node];
    }
    __syncthreads();

    if (threadIdx.x < 64) {
        int i = blockIdx.x * 64 + threadIdx.x;
        if (i < N_NODES) {
            float inv = 1.0f / fmaxf(sAcc[threadIdx.x][IN_CH], 1.0f);
            float ag[IN_CH], xa[IN_CH];
            #pragma unroll
            for (int c = 0; c < IN_CH; c++) ag[c] = sAcc[threadIdx.x][c] * inv;
            const float4* xp = (const float4*)(x + (size_t)i * IN_CH);
            float4 x0 = xp[0], x1 = xp[1];
            xa[0] = x0.x; xa[1] = x0.y; xa[2] = x0.z; xa[3] = x0.w;
            xa[4] = x1.x; xa[5] = x1.y; xa[6] = x1.z; xa[7] = x1.w;

            float g0 = 0.f, g1 = 0.f, r0 = 0.f, r1 = 0.f;
            #pragma unroll 8
            for (int kk = 0; kk < HID_CH; kk++) {
                float hk = sb[kk];
                #pragma unroll
                for (int c = 0; c < IN_CH; c++) {
                    hk += sWl[kk * IN_CH + c] * ag[c];
                    hk += sWr[kk * IN_CH + c] * xa[c];
                }
                hk = fmaxf(hk, 0.0f);   // ReLU (dropout identity in eval)
                g0 += sWl2[kk] * hk;
                g1 += sWl2[HID_CH + kk] * hk;
                r0 += sWr2[kk] * hk;
                r1 += sWr2[HID_CH + kk] * hk;
            }
            g[(size_t)i * 2 + 0] = g0;
            g[(size_t)i * 2 + 1] = g1;
            float2 r;
            r.x = r0 + sb2[0];
            r.y = r1 + sb2[1];
            *(float2*)(out_rt + (size_t)i * 2) = r;
        }
    }
}

// 4 lanes per node over the same CSR, summing g[src] (2ch);
// out = sum/max(deg,1) + rt (rt already parked in out by gather1).
__global__ __launch_bounds__(256) void gather2_csr(
        const int* __restrict__ csr, const int* __restrict__ off,
        const int* __restrict__ deg,
        const float* __restrict__ g, float* __restrict__ out) {
    int t = blockIdx.x * blockDim.x + threadIdx.x;
    int node = t >> 2;
    int k = t & 3;

    float a0 = 0.f, a1 = 0.f;
    int dn = 0;
    if (node < N_NODES) {
        int start = off[node];
        dn = deg[node];
        for (int j = k; j < dn; j += 4) {
            int s = csr[start + j];
            float2 gv = *(const float2*)(g + (size_t)s * 2);
            a0 += gv.x;
            a1 += gv.y;
        }
    }
    a0 += __shfl_xor(a0, 1, 4);
    a0 += __shfl_xor(a0, 2, 4);
    a1 += __shfl_xor(a1, 1, 4);
    a1 += __shfl_xor(a1, 2, 4);

    if (k == 0 && node < N_NODES) {
        float inv = 1.0f / fmaxf((float)dn, 1.0f);
        float2 r = *(const float2*)(out + (size_t)node * 2);
        float2 o;
        o.x = a0 * inv + r.x;
        o.y = a1 * inv + r.y;
        *(float2*)(out + (size_t)node * 2) = o;
    }
}

extern "C" void kernel_launch(void* const* d_in, const int* in_sizes, int n_in,
                              void* d_out, int out_size, void* d_ws, size_t ws_size,
                              hipStream_t stream) {
    const float* x    = (const float*)d_in[0];
    const int*   ei   = (const int*)d_in[1];   // [2, N_EDGES] int32 per harness
    const float* W_l1 = (const float*)d_in[2];
    const float* b_l1 = (const float*)d_in[3];
    const float* W_r1 = (const float*)d_in[4];
    const float* W_l2 = (const float*)d_in[5];
    const float* b_l2 = (const float*)d_in[6];
    const float* W_r2 = (const float*)d_in[7];
    float* out = (float*)d_out;

    const int* src = ei;
    const int* dst = ei + N_EDGES;

    int*   deg  = (int*)d_ws + WS_DEG;
    int*   off  = (int*)d_ws + WS_OFF;
    int*   bsum = (int*)d_ws + WS_BSUM;
    int*   rank = (int*)d_ws + WS_RANK;
    int*   csr  = (int*)d_ws + WS_CSR;
    float* g    = (float*)d_ws + WS_G;

    hipMemsetAsync(deg, 0, (size_t)N_NODES * sizeof(int), stream);

    const int BT = 256;
    int eblocks  = (N_EDGES + BT - 1) / BT;
    int nblocks4 = (4 * N_NODES + BT - 1) / BT;

    count_rank<<<eblocks, BT, 0, stream>>>(dst, deg, rank);
    scan1<<<SCAN_BLOCKS, 256, 0, stream>>>(deg, off, bsum);
    scan2<<<1, 128, 0, stream>>>(bsum);
    scan3<<<(N_NODES + BT - 1) / BT, BT, 0, stream>>>(off, bsum);
    scatter_csr<<<eblocks, BT, 0, stream>>>(src, dst, rank, off, csr);
    gather1_csr<<<nblocks4, BT, 0, stream>>>(csr, off, deg, x,
                                             W_l1, b_l1, W_r1, W_l2, b_l2, W_r2,
                                             g, out);
    gather2_csr<<<nblocks4, BT, 0, stream>>>(csr, off, deg, g, out);
}